// Round 6
// baseline (673.704 us; speedup 1.0000x reference)
//
#include <hip/hip_runtime.h>
#include <hip/hip_bf16.h>
#include <stdint.h>

#define BATCH 2048
#define FDIM 512
#define CDIM 64

typedef unsigned short ushort_t;
typedef __attribute__((ext_vector_type(8))) short short8;
typedef __attribute__((ext_vector_type(4))) float f32x4;

__device__ __forceinline__ ushort_t f2bf(float x) {
    union { float f; uint32_t u; } v; v.f = x;
    uint32_t u = v.u;
    uint32_t r = u + 0x7FFFu + ((u >> 16) & 1u);  // round-to-nearest-even
    return (ushort_t)(r >> 16);
}
__device__ __forceinline__ float bf2f(ushort_t u) {
    union { float f; uint32_t v; } x; x.v = ((uint32_t)u) << 16; return x.f;
}

// ---- prep: cast W_proj, f_feat, t_feat to bf16 (8 elems/thread) + zero counters ----
#define WCH ((CDIM * FDIM * FDIM) / 8)      // 2,097,152 8-elem chunks
#define FCH ((BATCH * FDIM) / 8)            // 131,072

__global__ void prep_kernel(const float* __restrict__ W, ushort_t* __restrict__ Wb,
                            const float* __restrict__ f, ushort_t* __restrict__ f16,
                            const float* __restrict__ t, ushort_t* __restrict__ t16,
                            unsigned int* __restrict__ cnt) {
    if (blockIdx.x == 0 && threadIdx.x < 16) cnt[threadIdx.x] = 0;
    int gid = blockIdx.x * 256 + threadIdx.x;
    const float* src; ushort_t* dst; int idx;
    if (gid < WCH)            { src = W; dst = Wb;  idx = gid; }
    else if (gid < WCH + FCH) { src = f; dst = f16; idx = gid - WCH; }
    else                      { src = t; dst = t16; idx = gid - WCH - FCH; }
    float4 v0 = ((const float4*)src)[idx * 2];
    float4 v1 = ((const float4*)src)[idx * 2 + 1];
    ushort_t p[8] = { f2bf(v0.x), f2bf(v0.y), f2bf(v0.z), f2bf(v0.w),
                      f2bf(v1.x), f2bf(v1.y), f2bf(v1.z), f2bf(v1.w) };
    *(uint4*)&dst[idx * 8] = *(uint4*)p;
}

// ---- fused GEMM (flipped, R2/R5-proven loop) + last-block MLP tail ----
// u[b,n] = sum_j f16[b,j]*Wb[n,j], n = c*512+i
// part[b,c,iq] = sum_i u[b,n] * t16[b,i]
// last block per b-tile: proj->relu->64x32 relu->32x1 -> out
#define AS3(p) ((__attribute__((address_space(3))) void*)(p))
#define AS1(p) ((const __attribute__((address_space(1))) void*)(p))

__launch_bounds__(256, 2)
__global__ void gemm_fused_kernel(const ushort_t* __restrict__ f16,
                                  const ushort_t* __restrict__ Wb,
                                  const ushort_t* __restrict__ t16,
                                  float* __restrict__ part,
                                  unsigned int* __restrict__ cnt,
                                  const float* __restrict__ b_proj,
                                  const float* __restrict__ W1,
                                  const float* __restrict__ b1,
                                  const float* __restrict__ W2,
                                  const float* __restrict__ b2,
                                  float* __restrict__ out) {
    __shared__ ushort_t As[128 * 32];   // [row=b][k=j] 64B rows, chunk-swizzled
    __shared__ ushort_t Bs[128 * 32];   // row-permuted + chunk-swizzled
    __shared__ float scratch[256];
    __shared__ int is_last;

    const int tid  = threadIdx.x;
    const int wave = tid >> 6;
    const int lane = tid & 63;
    const int l15  = lane & 15;
    const int lg   = lane >> 4;

    const int b0 = blockIdx.x * 128;
    const int n0 = blockIdx.y * 128;    // n = c*512 + i

    const int m_base = (wave >> 1) * 64;
    const int nh     = wave & 1;
    const int n_base = nh * 64;

    f32x4 acc[4][4];
    #pragma unroll
    for (int mi = 0; mi < 4; mi++)
        #pragma unroll
        for (int ni = 0; ni < 4; ni++)
            acc[mi][ni] = (f32x4){0.f, 0.f, 0.f, 0.f};

    // staging: lane tid -> phys (row p, chunk cph); content: global chunk cg = cph ^ ((p>>1)&3)
    // B row-permute: phys row p holds global n_local = ((p&15)<<2) | (p>>4)
    const int p    = tid >> 2;
    const int cph  = tid & 3;
    const int cg   = cph ^ ((p >> 1) & 3);
    const int nrot = ((p & 15) << 2) | (p >> 4);

    const ushort_t* gA0 = f16 + (size_t)(b0 + p) * FDIM + cg * 8;
    const ushort_t* gA1 = f16 + (size_t)(b0 + 64 + p) * FDIM + cg * 8;
    const ushort_t* gB0 = Wb + (size_t)(n0 + nrot) * FDIM + cg * 8;
    const ushort_t* gB1 = Wb + (size_t)(n0 + 64 + nrot) * FDIM + cg * 8;

    for (int k0 = 0; k0 < FDIM; k0 += 32) {
        __builtin_amdgcn_global_load_lds(AS1(gA0 + k0), AS3(&As[0 * 2048 + wave * 512]), 16, 0, 0);
        __builtin_amdgcn_global_load_lds(AS1(gA1 + k0), AS3(&As[1 * 2048 + wave * 512]), 16, 0, 0);
        __builtin_amdgcn_global_load_lds(AS1(gB0 + k0), AS3(&Bs[0 * 2048 + wave * 512]), 16, 0, 0);
        __builtin_amdgcn_global_load_lds(AS1(gB1 + k0), AS3(&Bs[1 * 2048 + wave * 512]), 16, 0, 0);
        __syncthreads();

        short8 a[4], b[4];
        #pragma unroll
        for (int mi = 0; mi < 4; mi++) {
            int r = m_base + mi * 16 + l15;
            a[mi] = *(const short8*)&As[r * 32 + (lg ^ ((r >> 1) & 3)) * 8];
        }
        #pragma unroll
        for (int ni = 0; ni < 4; ni++) {
            int q = n_base + ni * 16 + l15;
            b[ni] = *(const short8*)&Bs[q * 32 + (lg ^ ((q >> 1) & 3)) * 8];
        }

        #pragma unroll
        for (int mi = 0; mi < 4; mi++)
            #pragma unroll
            for (int ni = 0; ni < 4; ni++)
                acc[mi][ni] = __builtin_amdgcn_mfma_f32_16x16x32_bf16(a[mi], b[ni], acc[mi][ni], 0, 0, 0);

        __syncthreads();
    }

    // Epilogue: contract with t (bf16, 8B loads). D col l15 of frag ni holds
    // n = n0 + n_base + l15*4 + ni (4 consecutive i). D row = lg*4 + reg -> b.
    const int c  = n0 >> 9;
    const int iq = (n0 >> 7) & 3;
    const int i_base = (n0 & 511) + n_base + l15 * 4;

    #pragma unroll
    for (int mi = 0; mi < 4; mi++) {
        #pragma unroll
        for (int r = 0; r < 4; r++) {
            int b_idx = b0 + m_base + mi * 16 + lg * 4 + r;
            ushort4 tv = *(const ushort4*)&t16[(size_t)b_idx * FDIM + i_base];
            float sv = acc[mi][0][r] * bf2f(tv.x) + acc[mi][1][r] * bf2f(tv.y)
                     + acc[mi][2][r] * bf2f(tv.z) + acc[mi][3][r] * bf2f(tv.w);
            sv += __shfl_xor(sv, 1, 64);
            sv += __shfl_xor(sv, 2, 64);
            sv += __shfl_xor(sv, 4, 64);
            sv += __shfl_xor(sv, 8, 64);
            if (l15 == 0)
                scratch[(m_base + mi * 16 + lg * 4 + r) * 2 + nh] = sv;
        }
    }
    __syncthreads();
    if (tid < 128) {
        float v = scratch[tid * 2] + scratch[tid * 2 + 1];
        part[(((size_t)(b0 + tid)) * 64 + c) * 4 + iq] = v;
    }

    // ---- last-block-per-b-tile MLP tail ----
    __threadfence();                              // release: part writes device-visible
    if (tid == 0) {
        unsigned int old = atomicAdd(&cnt[blockIdx.x], 1u);
        is_last = (old == 255u);                  // 256 n-tiles per b-tile
    }
    __syncthreads();
    if (is_last) {
        __threadfence();                          // acquire: see all other blocks' part
        if (tid < 128) {
            int row = b0 + tid;
            const float4* p4 = (const float4*)&part[(size_t)row * 256];
            float h[64];
            #pragma unroll
            for (int cc = 0; cc < 64; cc++) {
                float4 v = p4[cc];
                float sv = v.x + v.y + v.z + v.w + b_proj[cc];
                h[cc] = sv > 0.f ? sv : 0.f;
            }
            float logit = b2[0];
            for (int o = 0; o < 32; o++) {
                float sv = b1[o];
                #pragma unroll
                for (int cc = 0; cc < 64; cc++) sv += h[cc] * W1[o * 64 + cc];
                logit += (sv > 0.f ? sv : 0.f) * W2[o];
            }
            out[row] = logit;
        }
    }
}

extern "C" void kernel_launch(void* const* d_in, const int* in_sizes, int n_in,
                              void* d_out, int out_size, void* d_ws, size_t ws_size,
                              hipStream_t stream) {
    const float* t_feat = (const float*)d_in[0];
    const float* f_feat = (const float*)d_in[1];
    const float* W_proj = (const float*)d_in[2];
    const float* b_proj = (const float*)d_in[3];
    const float* W1     = (const float*)d_in[4];
    const float* b1     = (const float*)d_in[5];
    const float* W2     = (const float*)d_in[6];
    const float* b2     = (const float*)d_in[7];
    float* out = (float*)d_out;

    uint8_t* ws = (uint8_t*)d_ws;
    ushort_t* Wb   = (ushort_t*)(ws);                          // 32 MiB
    ushort_t* f16  = (ushort_t*)(ws + 33554432);               // 2 MiB
    ushort_t* t16  = (ushort_t*)(ws + 35651584);               // 2 MiB
    float*    part = (float*)(ws + 37748736);                  // 2 MiB
    unsigned int* cnt = (unsigned int*)(ws + 39845888);        // 16 u32

    prep_kernel<<<dim3(WCH / 256 + (2 * FCH) / 256), dim3(256), 0, stream>>>(
        W_proj, Wb, f_feat, f16, t_feat, t16, cnt);

    gemm_fused_kernel<<<dim3(BATCH / 128, (CDIM * FDIM) / 128), dim3(256), 0, stream>>>(
        f16, Wb, t16, part, cnt, b_proj, W1, b1, W2, b2, out);
}

// Round 7
// 364.694 us; speedup vs baseline: 1.8473x; 1.8473x over previous
//
#include <hip/hip_runtime.h>
#include <hip/hip_bf16.h>
#include <stdint.h>

#define BATCH 2048
#define FDIM 512
#define CDIM 64

typedef unsigned short ushort_t;
typedef __attribute__((ext_vector_type(8))) short short8;
typedef __attribute__((ext_vector_type(4))) float f32x4;

__device__ __forceinline__ ushort_t f2bf(float x) {
    union { float f; uint32_t u; } v; v.f = x;
    uint32_t u = v.u;
    uint32_t r = u + 0x7FFFu + ((u >> 16) & 1u);  // round-to-nearest-even
    return (ushort_t)(r >> 16);
}
__device__ __forceinline__ float bf2f(ushort_t u) {
    union { float f; uint32_t v; } x; x.v = ((uint32_t)u) << 16; return x.f;
}

// ---- prep: cast f_feat and t_feat to bf16 (8 elems/thread) ----
#define FCH ((BATCH * FDIM) / 8)            // 131,072 chunks each

__global__ void prep_kernel(const float* __restrict__ f, ushort_t* __restrict__ f16,
                            const float* __restrict__ t, ushort_t* __restrict__ t16) {
    int gid = blockIdx.x * 256 + threadIdx.x;
    const float* src = (gid < FCH) ? f : t;
    ushort_t* dst    = (gid < FCH) ? f16 : t16;
    int idx = gid & (FCH - 1);
    float4 v0 = ((const float4*)src)[idx * 2];
    float4 v1 = ((const float4*)src)[idx * 2 + 1];
    ushort_t p[8] = { f2bf(v0.x), f2bf(v0.y), f2bf(v0.z), f2bf(v0.w),
                      f2bf(v1.x), f2bf(v1.y), f2bf(v1.z), f2bf(v1.w) };
    *(uint4*)&dst[idx * 8] = *(uint4*)p;
}

// ---- fused GEMM: u[b,n] = sum_j f16[b,j] * W[n,j]  (n = c*512 + i)
//      A (f16) staged bf16 via global_load_lds (R5-proven path).
//      B read DIRECTLY from fp32 W global -> VGPR -> cvt bf16 (no LDS, no Wb copy).
//      epilogue: part[b,c,iq] = sum_{i in tile} u[b,n] * t16[b,i]
#define AS3(p) ((__attribute__((address_space(3))) void*)(p))
#define AS1(p) ((const __attribute__((address_space(1))) void*)(p))

__launch_bounds__(256, 4)
__global__ void gemm_fused_kernel(const ushort_t* __restrict__ f16,
                                  const float* __restrict__ W,
                                  const ushort_t* __restrict__ t16,
                                  float* __restrict__ part) {
    __shared__ ushort_t As[128 * 32];   // [row=b][k=j] 64B rows, chunk-swizzled
    __shared__ float scratch[256];

    const int tid  = threadIdx.x;
    const int wave = tid >> 6;
    const int lane = tid & 63;
    const int l15  = lane & 15;
    const int lg   = lane >> 4;

    // XCD swizzle: xcd = g&7 owns n-tiles [xcd*32, xcd*32+32); b-tiles innermost
    // so one n-tile's 16 blocks are near-in-time on one XCD (W L2-resident).
    const int g  = blockIdx.x;
    const int s  = g >> 3;
    const int b0 = (s & 15) << 7;
    const int n0 = (((g & 7) << 5) + (s >> 4)) << 7;   // n = c*512 + i

    const int m_base = (wave >> 1) * 64;
    const int nh     = wave & 1;
    const int n_base = nh * 64;

    f32x4 acc[4][4];
    #pragma unroll
    for (int mi = 0; mi < 4; mi++)
        #pragma unroll
        for (int ni = 0; ni < 4; ni++)
            acc[mi][ni] = (f32x4){0.f, 0.f, 0.f, 0.f};

    // A staging: lane tid -> phys (row p, chunk cph); content chunk cg = cph ^ ((p>>1)&3)
    const int p   = tid >> 2;
    const int cph = tid & 3;
    const int cg  = cph ^ ((p >> 1) & 3);
    const ushort_t* gA0 = f16 + (size_t)(b0 + p) * FDIM + cg * 8;
    const ushort_t* gA1 = f16 + (size_t)(b0 + 64 + p) * FDIM + cg * 8;

    // B direct-load base: fragment ni needs global row n0 + n_base + l15*4 + ni,
    // k-cols lg*8..lg*8+7 (32B contiguous fp32 per lane; wave = 16 full lines).
    const float* gB = W + (size_t)(n0 + n_base + l15 * 4) * FDIM + lg * 8;

    for (int k0 = 0; k0 < FDIM; k0 += 32) {
        // B: global fp32 -> regs -> bf16 (per-frag to cap live fp32 regs)
        short8 b[4];
        #pragma unroll
        for (int ni = 0; ni < 4; ni++) {
            const float* bp = gB + (size_t)ni * FDIM + k0;
            float4 v0 = *(const float4*)bp;
            float4 v1 = *(const float4*)(bp + 4);
            union { __hip_bfloat162 h2[4]; short8 s8; } pk;
            pk.h2[0] = __float22bfloat162_rn(make_float2(v0.x, v0.y));
            pk.h2[1] = __float22bfloat162_rn(make_float2(v0.z, v0.w));
            pk.h2[2] = __float22bfloat162_rn(make_float2(v1.x, v1.y));
            pk.h2[3] = __float22bfloat162_rn(make_float2(v1.z, v1.w));
            b[ni] = pk.s8;
        }

        // A: async stage to LDS
        __builtin_amdgcn_global_load_lds(AS1(gA0 + k0), AS3(&As[0 * 2048 + wave * 512]), 16, 0, 0);
        __builtin_amdgcn_global_load_lds(AS1(gA1 + k0), AS3(&As[1 * 2048 + wave * 512]), 16, 0, 0);
        __syncthreads();

        short8 a[4];
        #pragma unroll
        for (int mi = 0; mi < 4; mi++) {
            int r = m_base + mi * 16 + l15;
            a[mi] = *(const short8*)&As[r * 32 + (lg ^ ((r >> 1) & 3)) * 8];
        }

        #pragma unroll
        for (int mi = 0; mi < 4; mi++)
            #pragma unroll
            for (int ni = 0; ni < 4; ni++)
                acc[mi][ni] = __builtin_amdgcn_mfma_f32_16x16x32_bf16(a[mi], b[ni], acc[mi][ni], 0, 0, 0);

        __syncthreads();
    }

    // Epilogue: D col l15 of frag ni holds global n = n0 + n_base + l15*4 + ni
    // (4 consecutive i per lane). D row = lg*4 + reg -> b. t read as bf16x4 (8B).
    const int c  = n0 >> 9;
    const int iq = (n0 >> 7) & 3;
    const int i_base = (n0 & 511) + n_base + l15 * 4;

    #pragma unroll
    for (int mi = 0; mi < 4; mi++) {
        #pragma unroll
        for (int r = 0; r < 4; r++) {
            int b_idx = b0 + m_base + mi * 16 + lg * 4 + r;
            ushort4 tv = *(const ushort4*)&t16[(size_t)b_idx * FDIM + i_base];
            float sv = acc[mi][0][r] * bf2f(tv.x) + acc[mi][1][r] * bf2f(tv.y)
                     + acc[mi][2][r] * bf2f(tv.z) + acc[mi][3][r] * bf2f(tv.w);
            sv += __shfl_xor(sv, 1, 64);
            sv += __shfl_xor(sv, 2, 64);
            sv += __shfl_xor(sv, 4, 64);
            sv += __shfl_xor(sv, 8, 64);
            if (l15 == 0)
                scratch[(m_base + mi * 16 + lg * 4 + r) * 2 + nh] = sv;
        }
    }
    __syncthreads();
    if (tid < 128) {
        float v = scratch[tid * 2] + scratch[tid * 2 + 1];
        part[(((size_t)(b0 + tid)) * 64 + c) * 4 + iq] = v;
    }
}

// ---- MLP head: 32 threads per batch row, shuffle-reduced ----
__global__ void mlp_kernel(const float* __restrict__ part,
                           const float* __restrict__ b_proj,
                           const float* __restrict__ W1, const float* __restrict__ b1,
                           const float* __restrict__ W2, const float* __restrict__ b2,
                           float* __restrict__ out) {
    __shared__ float h[8][64];
    const int tid = threadIdx.x;
    const int bl  = tid >> 5;        // 0..7
    const int o   = tid & 31;
    const int b   = blockIdx.x * 8 + bl;

    #pragma unroll
    for (int c = o; c < 64; c += 32) {
        float4 v = *(const float4*)&part[(((size_t)b * 64 + c)) * 4];
        float sv = v.x + v.y + v.z + v.w + b_proj[c];
        h[bl][c] = sv > 0.f ? sv : 0.f;
    }
    __syncthreads();

    float sv = b1[o];
    #pragma unroll
    for (int c = 0; c < 64; c++) sv += h[bl][c] * W1[o * 64 + c];
    float v = (sv > 0.f ? sv : 0.f) * W2[o];
    v += __shfl_xor(v, 1, 32);
    v += __shfl_xor(v, 2, 32);
    v += __shfl_xor(v, 4, 32);
    v += __shfl_xor(v, 8, 32);
    v += __shfl_xor(v, 16, 32);
    if (o == 0) out[b] = v + b2[0];
}

extern "C" void kernel_launch(void* const* d_in, const int* in_sizes, int n_in,
                              void* d_out, int out_size, void* d_ws, size_t ws_size,
                              hipStream_t stream) {
    const float* t_feat = (const float*)d_in[0];
    const float* f_feat = (const float*)d_in[1];
    const float* W_proj = (const float*)d_in[2];
    const float* b_proj = (const float*)d_in[3];
    const float* W1     = (const float*)d_in[4];
    const float* b1     = (const float*)d_in[5];
    const float* W2     = (const float*)d_in[6];
    const float* b2     = (const float*)d_in[7];
    float* out = (float*)d_out;

    uint8_t* ws = (uint8_t*)d_ws;
    ushort_t* f16  = (ushort_t*)(ws);                 // 2 MiB
    ushort_t* t16  = (ushort_t*)(ws + 2097152);       // 2 MiB
    float*    part = (float*)(ws + 4194304);          // 2 MiB

    prep_kernel<<<dim3((2 * FCH) / 256), dim3(256), 0, stream>>>(f_feat, f16, t_feat, t16);

    gemm_fused_kernel<<<dim3(4096), dim3(256), 0, stream>>>(f16, W_proj, t16, part);

    mlp_kernel<<<dim3(BATCH / 8), dim3(256), 0, stream>>>(part, b_proj, W1, b1, W2, b2, out);
}

// Round 8
// 214.815 us; speedup vs baseline: 3.1362x; 1.6977x over previous
//
#include <hip/hip_runtime.h>
#include <hip/hip_bf16.h>
#include <stdint.h>

#define BATCH 2048
#define FDIM 512
#define CDIM 64

typedef unsigned short ushort_t;
typedef __attribute__((ext_vector_type(8))) short short8;
typedef __attribute__((ext_vector_type(4))) float f32x4;

__device__ __forceinline__ ushort_t f2bf(float x) {
    union { float f; uint32_t u; } v; v.f = x;
    uint32_t u = v.u;
    uint32_t r = u + 0x7FFFu + ((u >> 16) & 1u);  // round-to-nearest-even
    return (ushort_t)(r >> 16);
}
__device__ __forceinline__ float bf2f(ushort_t u) {
    union { float f; uint32_t v; } x; x.v = ((uint32_t)u) << 16; return x.f;
}

// ---- fp32 -> bf16 cast, 8 elems / thread, 16B stores (W_proj) ----
__global__ void convert_kernel(const float* __restrict__ src, ushort_t* __restrict__ dst) {
    int idx = blockIdx.x * 256 + threadIdx.x;
    float4 v0 = ((const float4*)src)[idx * 2];
    float4 v1 = ((const float4*)src)[idx * 2 + 1];
    ushort_t p[8] = { f2bf(v0.x), f2bf(v0.y), f2bf(v0.z), f2bf(v0.w),
                      f2bf(v1.x), f2bf(v1.y), f2bf(v1.z), f2bf(v1.w) };
    *(uint4*)&dst[idx * 8] = *(uint4*)p;
}

// ---- fused convert for f_feat and t_feat (1M elems each) ----
__global__ void convert_ft_kernel(const float* __restrict__ f, ushort_t* __restrict__ f16,
                                  const float* __restrict__ t, ushort_t* __restrict__ t16) {
    int blk = blockIdx.x;
    const float* src = (blk < 512) ? f : t;
    ushort_t* dst    = (blk < 512) ? f16 : t16;
    int idx = (blk & 511) * 256 + threadIdx.x;
    float4 v0 = ((const float4*)src)[idx * 2];
    float4 v1 = ((const float4*)src)[idx * 2 + 1];
    ushort_t p[8] = { f2bf(v0.x), f2bf(v0.y), f2bf(v0.z), f2bf(v0.w),
                      f2bf(v1.x), f2bf(v1.y), f2bf(v1.z), f2bf(v1.w) };
    *(uint4*)&dst[idx * 8] = *(uint4*)p;
}

// ---- fused GEMM (flipped, R2/R5-proven structure): u[b,n] = sum_j f16[b,j]*Wb[n,j]
//      n = c*512 + i;  epilogue: part[b,c,iq] = sum_i u[b,n] * t16[b,i]
#define AS3(p) ((__attribute__((address_space(3))) void*)(p))
#define AS1(p) ((const __attribute__((address_space(1))) void*)(p))

__launch_bounds__(256, 4)
__global__ void gemm_fused_kernel(const ushort_t* __restrict__ f16,
                                  const ushort_t* __restrict__ Wb,
                                  const ushort_t* __restrict__ t16,
                                  float* __restrict__ part) {
    __shared__ ushort_t As[128 * 32];   // [row=b][k=j] 64B rows, chunk-swizzled
    __shared__ ushort_t Bs[128 * 32];   // row-permuted + chunk-swizzled
    __shared__ float scratch[256];

    const int tid  = threadIdx.x;
    const int wave = tid >> 6;
    const int lane = tid & 63;
    const int l15  = lane & 15;
    const int lg   = lane >> 4;

    const int b0 = blockIdx.x * 128;
    const int n0 = blockIdx.y * 128;    // n = c*512 + i

    const int m_base = (wave >> 1) * 64;
    const int nh     = wave & 1;
    const int n_base = nh * 64;

    f32x4 acc[4][4];
    #pragma unroll
    for (int mi = 0; mi < 4; mi++)
        #pragma unroll
        for (int ni = 0; ni < 4; ni++)
            acc[mi][ni] = (f32x4){0.f, 0.f, 0.f, 0.f};

    // staging: lane tid -> phys (row p, chunk cph); content: global chunk cg = cph ^ ((p>>1)&3)
    // B row-permute: phys row p holds global n_local = ((p&15)<<2) | (p>>4)
    const int p    = tid >> 2;
    const int cph  = tid & 3;
    const int cg   = cph ^ ((p >> 1) & 3);
    const int nrot = ((p & 15) << 2) | (p >> 4);

    const ushort_t* gA0 = f16 + (size_t)(b0 + p) * FDIM + cg * 8;
    const ushort_t* gA1 = f16 + (size_t)(b0 + 64 + p) * FDIM + cg * 8;
    const ushort_t* gB0 = Wb + (size_t)(n0 + nrot) * FDIM + cg * 8;
    const ushort_t* gB1 = Wb + (size_t)(n0 + 64 + nrot) * FDIM + cg * 8;

    for (int k0 = 0; k0 < FDIM; k0 += 32) {
        __builtin_amdgcn_global_load_lds(AS1(gA0 + k0), AS3(&As[0 * 2048 + wave * 512]), 16, 0, 0);
        __builtin_amdgcn_global_load_lds(AS1(gA1 + k0), AS3(&As[1 * 2048 + wave * 512]), 16, 0, 0);
        __builtin_amdgcn_global_load_lds(AS1(gB0 + k0), AS3(&Bs[0 * 2048 + wave * 512]), 16, 0, 0);
        __builtin_amdgcn_global_load_lds(AS1(gB1 + k0), AS3(&Bs[1 * 2048 + wave * 512]), 16, 0, 0);
        __syncthreads();

        short8 a[4], b[4];
        #pragma unroll
        for (int mi = 0; mi < 4; mi++) {
            int r = m_base + mi * 16 + l15;
            a[mi] = *(const short8*)&As[r * 32 + (lg ^ ((r >> 1) & 3)) * 8];
        }
        #pragma unroll
        for (int ni = 0; ni < 4; ni++) {
            int q = n_base + ni * 16 + l15;
            b[ni] = *(const short8*)&Bs[q * 32 + (lg ^ ((q >> 1) & 3)) * 8];
        }

        #pragma unroll
        for (int mi = 0; mi < 4; mi++)
            #pragma unroll
            for (int ni = 0; ni < 4; ni++)
                acc[mi][ni] = __builtin_amdgcn_mfma_f32_16x16x32_bf16(a[mi], b[ni], acc[mi][ni], 0, 0, 0);

        __syncthreads();
    }

    // Epilogue. D col l15 of frag ni holds global n = n0 + n_base + l15*4 + ni
    // (4 consecutive i per lane). D row = lg*4 + reg -> b. t read as bf16x4 (8B).
    const int c  = n0 >> 9;
    const int iq = (n0 >> 7) & 3;
    const int i_base = (n0 & 511) + n_base + l15 * 4;

    #pragma unroll
    for (int mi = 0; mi < 4; mi++) {
        #pragma unroll
        for (int r = 0; r < 4; r++) {
            int b_idx = b0 + m_base + mi * 16 + lg * 4 + r;
            ushort4 tv = *(const ushort4*)&t16[(size_t)b_idx * FDIM + i_base];
            float sv = acc[mi][0][r] * bf2f(tv.x) + acc[mi][1][r] * bf2f(tv.y)
                     + acc[mi][2][r] * bf2f(tv.z) + acc[mi][3][r] * bf2f(tv.w);
            sv += __shfl_xor(sv, 1, 64);
            sv += __shfl_xor(sv, 2, 64);
            sv += __shfl_xor(sv, 4, 64);
            sv += __shfl_xor(sv, 8, 64);
            if (l15 == 0)
                scratch[(m_base + mi * 16 + lg * 4 + r) * 2 + nh] = sv;
        }
    }
    __syncthreads();
    if (tid < 128) {
        float v = scratch[tid * 2] + scratch[tid * 2 + 1];
        part[(((size_t)(b0 + tid)) * 64 + c) * 4 + iq] = v;
    }
}

// ---- MLP head: 32 threads per batch row, shuffle-reduced ----
__global__ void mlp_kernel(const float* __restrict__ part,
                           const float* __restrict__ b_proj,
                           const float* __restrict__ W1, const float* __restrict__ b1,
                           const float* __restrict__ W2, const float* __restrict__ b2,
                           float* __restrict__ out) {
    __shared__ float h[8][64];
    const int tid = threadIdx.x;
    const int bl  = tid >> 5;        // 0..7
    const int o   = tid & 31;
    const int b   = blockIdx.x * 8 + bl;

    #pragma unroll
    for (int c = o; c < 64; c += 32) {
        float4 v = *(const float4*)&part[(((size_t)b * 64 + c)) * 4];
        float sv = v.x + v.y + v.z + v.w + b_proj[c];
        h[bl][c] = sv > 0.f ? sv : 0.f;
    }
    __syncthreads();

    float sv = b1[o];
    #pragma unroll
    for (int c = 0; c < 64; c++) sv += h[bl][c] * W1[o * 64 + c];
    float v = (sv > 0.f ? sv : 0.f) * W2[o];
    v += __shfl_xor(v, 1, 32);
    v += __shfl_xor(v, 2, 32);
    v += __shfl_xor(v, 4, 32);
    v += __shfl_xor(v, 8, 32);
    v += __shfl_xor(v, 16, 32);
    if (o == 0) out[b] = v + b2[0];
}

extern "C" void kernel_launch(void* const* d_in, const int* in_sizes, int n_in,
                              void* d_out, int out_size, void* d_ws, size_t ws_size,
                              hipStream_t stream) {
    const float* t_feat = (const float*)d_in[0];
    const float* f_feat = (const float*)d_in[1];
    const float* W_proj = (const float*)d_in[2];
    const float* b_proj = (const float*)d_in[3];
    const float* W1     = (const float*)d_in[4];
    const float* b1     = (const float*)d_in[5];
    const float* W2     = (const float*)d_in[6];
    const float* b2     = (const float*)d_in[7];
    float* out = (float*)d_out;

    uint8_t* ws = (uint8_t*)d_ws;
    ushort_t* Wb   = (ushort_t*)(ws);                          // 32 MiB
    ushort_t* f16  = (ushort_t*)(ws + 33554432);               // 2 MiB
    ushort_t* t16  = (ushort_t*)(ws + 33554432 + 2097152);     // 2 MiB
    float*    part = (float*)(ws + 33554432 + 2 * 2097152);    // 2 MiB

    convert_kernel<<<dim3((CDIM * FDIM * FDIM) / 2048), dim3(256), 0, stream>>>(W_proj, Wb);
    convert_ft_kernel<<<dim3(1024), dim3(256), 0, stream>>>(f_feat, f16, t_feat, t16);

    gemm_fused_kernel<<<dim3(BATCH / 128, (CDIM * FDIM) / 128), dim3(256), 0, stream>>>(
        f16, Wb, t16, part);

    mlp_kernel<<<dim3(BATCH / 8), dim3(256), 0, stream>>>(part, b_proj, W1, b1, W2, b2, out);
}